// Round 8
// baseline (186.248 us; speedup 1.0000x reference)
//
#include <hip/hip_runtime.h>
#include <hip/hip_bf16.h>
#include <math.h>

// loss = (1/C) * sum_i log( sum_j exp(<x_i,x_j>/T) ),  x: [16384, 256] fp32, unit rows.
// R7: R6 structure (global balanced lower-triangle partition, 512 blocks, A-in-regs,
// fragment-major LDS B, counted vmcnt(8), no atomics) with:
//  (a) 32x32x16 bf16 MFMA (+15% ceiling, half the MFMA instructions vs 16x16x32)
//  (b) s_setprio(1) around MFMA clusters (T5)

#define N_ROWS 16384
#define KD     256
#define NT     64                     // 256-row bands
#define NBLK   512                    // balanced partition: 65/16 tiles per block
#define NSLOT  96                     // rowacc slots: 0..63 col-path, 64..95 row-path

// exp(sim/T) = exp2( dot * (1/T)*log2 e ); sqrt folded into BOTH operands.
#define SCALE_SQRT 1.6986436f

typedef short short8 __attribute__((ext_vector_type(8)));   // 8 bf16 = 4 VGPRs
typedef float f32x16 __attribute__((ext_vector_type(16)));

typedef __attribute__((address_space(3))) void       lds_void;
typedef const __attribute__((address_space(1))) void gm_void;

__device__ __forceinline__ float fast_exp2(float x) {
#if __has_builtin(__builtin_amdgcn_exp2f)
    return __builtin_amdgcn_exp2f(x);
#else
    return exp2f(x);
#endif
}

__device__ __forceinline__ void gll16(const void* g, void* l) {
    __builtin_amdgcn_global_load_lds((gm_void*)g, (lds_void*)l, 16, 0, 0);
}

// ---------------- fp32 -> bf16 (RNE, pre-scaled) + zero rowacc/out ----------------
__global__ void convert_kernel(const float* __restrict__ x, unsigned short* __restrict__ xb,
                               float* __restrict__ rowacc, float* __restrict__ out) {
    const int bx = blockIdx.x, tid = threadIdx.x;
    if (bx < (NSLOT * N_ROWS) / 1024)
        *(float4*)(rowacc + (size_t)(bx * 256 + tid) * 4) = (float4){0.f, 0.f, 0.f, 0.f};
    if (bx == 2000 && tid == 0) out[0] = 0.f;
    int i = (bx * 256 + tid) * 4;
    float4 v = *(const float4*)(x + i);
    ushort4 o;
    {
        unsigned int u;
        u = __float_as_uint(v.x * SCALE_SQRT); u += 0x7fff + ((u >> 16) & 1); o.x = (unsigned short)(u >> 16);
        u = __float_as_uint(v.y * SCALE_SQRT); u += 0x7fff + ((u >> 16) & 1); o.y = (unsigned short)(u >> 16);
        u = __float_as_uint(v.z * SCALE_SQRT); u += 0x7fff + ((u >> 16) & 1); o.z = (unsigned short)(u >> 16);
        u = __float_as_uint(v.w * SCALE_SQRT); u += 0x7fff + ((u >> 16) & 1); o.w = (unsigned short)(u >> 16);
    }
    *(ushort4*)(xb + i) = o;
}

// ---------------- main fused kernel ----------------
// 256 thr = 4 waves; wave w owns rows [r0 + w*64, +64) as 2 m-frags of 32 rows.
// 32x32x16 layouts: A/B: row|col = lane&31, k = kt*16 + (lane>>5)*8 + j.
// C/D (HW-verified m74/m101): col = lane&31, row = (reg&3) + 8*(reg>>2) + 4*(lane>>5).
// B tile (64 cols) dbuf in LDS fragment-major: frag f = ct*16+kt at f*1024 + lane*16.
__global__ __launch_bounds__(256, 2)
void simloss_main(const unsigned short* __restrict__ xb, float* __restrict__ rowacc) {
    __shared__ __align__(128) char smem[65536 + 1024 + 4096];
    float* const rowred = (float*)(smem + 65536);          // [256]
    float* const colred = (float*)(smem + 65536 + 1024);   // [4][256]

    const int tid  = threadIdx.x;
    const int lane = tid & 63;
    const int w    = tid >> 6;                  // 0..3
    const int l31  = lane & 31;
    const int lh   = lane >> 5;                 // 0..1
    const int b    = blockIdx.x;

    int t          = (b * 65) >> 4;             // first tile (rb-major)
    const int tEnd = ((b + 1) * 65) >> 4;
    const int rowSlot = NT + (b & 31);

    int rb = (int)((sqrtf(8.f * (float)t + 1.f) - 1.f) * 0.5f);
    while ((rb + 1) * (rb + 2) / 2 <= t) ++rb;
    while (rb * (rb + 1) / 2 > t) --rb;

    #pragma unroll 1
    while (t < tEnd) {
        while ((rb + 1) * (rb + 2) / 2 <= t) ++rb;
        const int rowStart = rb * (rb + 1) / 2;
        const int cb0 = t - rowStart;
        const int tE  = tEnd - rowStart;
        const int cbE = tE < rb + 1 ? tE : rb + 1;
        const int NI  = (cbE - cb0) * 4;        // 64-col iterations
        const int r0  = rb * 256;
        const int colblk0 = cb0 * 4;

        auto stageB = [&](int buf, int cblk) {
            #pragma unroll
            for (int g = 0; g < 8; ++g) {
                const int fr = w * 8 + g;                   // frag id 0..31
                const int ct = fr >> 4, kt = fr & 15;
                const unsigned short* s =
                    xb + (size_t)(cblk * 64 + ct * 32 + l31) * KD + kt * 16 + lh * 8;
                gll16(s, smem + buf * 32768 + fr * 1024);
            }
        };
        stageB(0, colblk0);                     // B0 first so its latency overlaps A

        // A frags: af[m][kt], m-frag = 32 rows
        short8 af[2][16];
        #pragma unroll
        for (int m = 0; m < 2; ++m) {
            const unsigned short* ar = xb + (size_t)(r0 + w * 64 + m * 32 + l31) * KD + lh * 8;
            #pragma unroll
            for (int kt = 0; kt < 16; ++kt)
                af[m][kt] = *(const short8*)(ar + kt * 16);
        }
        #pragma unroll
        for (int m = 0; m < 2; ++m)
            #pragma unroll
            for (int kt = 0; kt < 16; ++kt)
                asm volatile("" : "+v"(af[m][kt]));         // pin (rolled loop -> AGPRs)

        float rowsum[32];
        #pragma unroll
        for (int r = 0; r < 32; ++r) rowsum[r] = 0.f;

        #pragma unroll 1                        // MUST stay rolled (R4 spill lesson)
        for (int fi = 0; fi < NI; ++fi) {
            const int cur = fi & 1;
            if (fi + 1 < NI) {
                stageB(cur ^ 1, colblk0 + fi + 1);
                asm volatile("s_waitcnt vmcnt(8)" ::: "memory");
            } else {
                asm volatile("s_waitcnt vmcnt(0)" ::: "memory");
            }
            __builtin_amdgcn_s_barrier();
            asm volatile("" ::: "memory");

            const char* bbase = smem + cur * 32768;
            #pragma unroll
            for (int ct = 0; ct < 2; ++ct) {
                f32x16 acc0, acc1;
                #pragma unroll
                for (int r = 0; r < 16; ++r) { acc0[r] = 0.f; acc1[r] = 0.f; }
                #pragma unroll
                for (int q = 0; q < 4; ++q) {   // 4 chunks of 4 kt (bfrag live = 16 regs)
                    short8 bf[4];
                    #pragma unroll
                    for (int j = 0; j < 4; ++j)             // lane-linear: zero conflicts
                        bf[j] = *(const short8*)(bbase + (ct * 16 + q * 4 + j) * 1024 + lane * 16);
                    __builtin_amdgcn_s_setprio(1);
                    #pragma unroll
                    for (int j = 0; j < 4; ++j) {
                        acc0 = __builtin_amdgcn_mfma_f32_32x32x16_bf16(af[0][q * 4 + j], bf[j], acc0, 0, 0, 0);
                        acc1 = __builtin_amdgcn_mfma_f32_32x32x16_bf16(af[1][q * 4 + j], bf[j], acc1, 0, 0, 0);
                    }
                    __builtin_amdgcn_s_setprio(0);
                }
                // exp2 + row/col partial sums
                float csum = 0.f;
                #pragma unroll
                for (int r = 0; r < 16; ++r) {
                    float e0 = fast_exp2(acc0[r]); rowsum[r]      += e0; csum += e0;
                    float e1 = fast_exp2(acc1[r]); rowsum[16 + r] += e1; csum += e1;
                }
                csum += __shfl_xor(csum, 32);   // add other 32-row half for this col
                if (lh == 0)
                    colred[w * 256 + (fi & 3) * 64 + ct * 32 + l31] = csum;
            }

            asm volatile("" ::: "memory");
            __builtin_amdgcn_s_barrier();
            asm volatile("" ::: "memory");

            if ((fi & 3) == 3) {                // tile boundary: flush col-sums (k=rb)
                const int cb = cb0 + (fi >> 2);
                if (cb != rb) {
                    float cs = colred[tid] + colred[256 + tid] + colred[512 + tid] + colred[768 + tid];
                    rowacc[(size_t)rb * N_ROWS + cb * 256 + tid] = cs;
                }
                // safe: next colred writes happen only after next fi's post-stage barrier
            }
        }

        // segment epilogue: row-sums (reduce over 32 col-lanes)
        #pragma unroll
        for (int m = 0; m < 2; ++m)
            #pragma unroll
            for (int r = 0; r < 16; ++r) {
                float v = rowsum[m * 16 + r];
                v += __shfl_xor(v, 1);
                v += __shfl_xor(v, 2);
                v += __shfl_xor(v, 4);
                v += __shfl_xor(v, 8);
                v += __shfl_xor(v, 16);
                if (l31 == 0)
                    rowred[w * 64 + m * 32 + (r & 3) + 8 * (r >> 2) + 4 * lh] = v;
            }
        __syncthreads();
        rowacc[(size_t)rowSlot * N_ROWS + r0 + tid] = rowred[tid];

        t = rowStart + cbE;
    }
}

// ---------------- finalize: loss = sum_i log( sum_k rowacc[k][i] ) / 100 ----------------
__global__ void finalize_kernel(const float* __restrict__ rowacc, float* __restrict__ out) {
    int i = blockIdx.x * 256 + threadIdx.x;
    float s = 0.f;
    #pragma unroll 8
    for (int k = 0; k < NSLOT; ++k) s += rowacc[(size_t)k * N_ROWS + i];
    float v = logf(s);
    #pragma unroll
    for (int off = 1; off < 64; off <<= 1) v += __shfl_xor(v, off);
    __shared__ float red[4];
    if ((threadIdx.x & 63) == 0) red[threadIdx.x >> 6] = v;
    __syncthreads();
    if (threadIdx.x == 0)
        atomicAdd(out, (red[0] + red[1] + red[2] + red[3]) * 0.01f);
}

extern "C" void kernel_launch(void* const* d_in, const int* in_sizes, int n_in,
                              void* d_out, int out_size, void* d_ws, size_t ws_size,
                              hipStream_t stream) {
    const float* x = (const float*)d_in[0];
    unsigned short* xb = (unsigned short*)d_ws;                           // 8 MB bf16 (pre-scaled)
    float* rowacc = (float*)((char*)d_ws + (size_t)N_ROWS * KD * 2);      // 96 x 16384 f32 (6 MB)
    float* out = (float*)d_out;

    convert_kernel<<<(N_ROWS * KD) / (256 * 4), 256, 0, stream>>>(x, xb, rowacc, out);
    simloss_main<<<NBLK, 256, 0, stream>>>(xb, rowacc);
    finalize_kernel<<<N_ROWS / 256, 256, 0, stream>>>(rowacc, out);
}

// Round 9
// 149.921 us; speedup vs baseline: 1.2423x; 1.2423x over previous
//
#include <hip/hip_runtime.h>
#include <hip/hip_bf16.h>
#include <math.h>

// loss = (1/C) * sum_i log( sum_j exp(<x_i,x_j>/T) ),  x: [16384, 256] fp32, unit rows.
// R8: revert R7's 32x32 (register spill, WRITE 19MB). Keep R6's proven 16x16x32 inner
// loop (fragment-major LDS B, lane-linear ds_read_b128, A pinned in regs/AGPRs) and
// attack the ~45% sync-stall: ring-4 LDS buffers, prefetch depth 2, ONE raw barrier
// per fi (ring distance 3 makes the post-compute barrier unnecessary), counted vmcnt,
// 512-thr blocks x 256 = exactly 1/CU, fi-balanced partition (16/17 fi per block),
// per-fi col-sum flush (unique-writer slots, no atomics).

#define N_ROWS 16384
#define KD     256
#define NBAND  32                     // 512-row bands
#define FI_TOTAL 4224                 // sum_rb 8*(rb+1)
#define NBLK   256                    // 1 block/CU
#define NSLOT  96                     // rowacc: 0..31 col-path(k=rb), 64..95 row-path

// exp(sim/T) = exp2( dot * (1/T)*log2 e ); sqrt folded into BOTH operands at convert.
#define SCALE_SQRT 1.6986436f

typedef short short8 __attribute__((ext_vector_type(8)));   // 8 bf16 = 4 VGPRs
typedef float f32x4  __attribute__((ext_vector_type(4)));

typedef __attribute__((address_space(3))) void       lds_void;
typedef const __attribute__((address_space(1))) void gm_void;

__device__ __forceinline__ float fast_exp2(float x) {
#if __has_builtin(__builtin_amdgcn_exp2f)
    return __builtin_amdgcn_exp2f(x);
#else
    return exp2f(x);
#endif
}

__device__ __forceinline__ void gll16(const void* g, void* l) {
    __builtin_amdgcn_global_load_lds((gm_void*)g, (lds_void*)l, 16, 0, 0);
}

// ---------------- fp32 -> bf16 (RNE, pre-scaled) + zero rowacc/out ----------------
__global__ void convert_kernel(const float* __restrict__ x, unsigned short* __restrict__ xb,
                               float* __restrict__ rowacc, float* __restrict__ out) {
    const int bx = blockIdx.x, tid = threadIdx.x;
    if (bx < (NSLOT * N_ROWS) / 1024)                       // 1536 blocks zero 4 floats each
        *(float4*)(rowacc + (size_t)(bx * 256 + tid) * 4) = (float4){0.f, 0.f, 0.f, 0.f};
    if (bx == 2000 && tid == 0) out[0] = 0.f;
    int i = (bx * 256 + tid) * 4;
    float4 v = *(const float4*)(x + i);
    ushort4 o;
    {
        unsigned int u;
        u = __float_as_uint(v.x * SCALE_SQRT); u += 0x7fff + ((u >> 16) & 1); o.x = (unsigned short)(u >> 16);
        u = __float_as_uint(v.y * SCALE_SQRT); u += 0x7fff + ((u >> 16) & 1); o.y = (unsigned short)(u >> 16);
        u = __float_as_uint(v.z * SCALE_SQRT); u += 0x7fff + ((u >> 16) & 1); o.z = (unsigned short)(u >> 16);
        u = __float_as_uint(v.w * SCALE_SQRT); u += 0x7fff + ((u >> 16) & 1); o.w = (unsigned short)(u >> 16);
    }
    *(ushort4*)(xb + i) = o;
}

// ---------------- main fused kernel ----------------
// 512 thr = 8 waves; wave w owns A rows [r0 + w*64, +64) (4 m-frags of 16, pinned).
// Global fi space: band rb (512 rows) has 8*(rb+1) fi of 64 cols; block b owns
// fi in [(b*33)>>1, ((b+1)*33)>>1). Ring-4 B buffers (32KB each), depth-2 prefetch,
// ONE s_barrier per fi. B frags staged fragment-major (1KB/frag, lane-linear reads).
__global__ __launch_bounds__(512, 2)
void simloss_main(const unsigned short* __restrict__ xb, float* __restrict__ rowacc) {
    __shared__ __align__(128) char smem[4 * 32768 + 2048 + 4096];
    float* const rowred = (float*)(smem + 131072);          // [512]
    float* const colred = (float*)(smem + 131072 + 2048);   // [2][8][64]

    const int tid  = threadIdx.x;
    const int lane = tid & 63;
    const int w    = tid >> 6;                  // 0..7
    const int l15  = lane & 15;
    const int lg   = lane >> 4;                 // 0..3
    const int b    = blockIdx.x;

    int f          = (b * 33) >> 1;             // 16.5 fi per block
    const int fEnd = ((b + 1) * 33) >> 1;
    const int rowSlot = 64 + (b & 31);          // blocks sharing a band span <=17 ids

    int rb = (int)((sqrtf((float)f + 1.f) - 1.f) * 0.5f);
    while (4 * (rb + 1) * (rb + 2) <= f) ++rb;
    while (4 * rb * (rb + 1) > f) --rb;

    #pragma unroll 1
    while (f < fEnd) {
        while (4 * (rb + 1) * (rb + 2) <= f) ++rb;          // advance band
        const int bandStart = 4 * rb * (rb + 1);
        const int cblk0   = f - bandStart;                  // first 64-col chunk
        const int bandEnd = bandStart + 8 * (rb + 1);
        const int lim = fEnd < bandEnd ? fEnd : bandEnd;
        const int NI  = lim - f;                            // fi in this segment
        const int r0  = rb * 512;

        auto stageB = [&](int buf, int cblk) {
            if (cblk > 255) cblk = 255;                     // clamp (staged-but-unused tail)
            #pragma unroll
            for (int g = 0; g < 4; ++g) {
                const int fr = w * 4 + g;                   // frag 0..31: ct=fr>>3, kt=fr&7
                const int ct = fr >> 3, kt = fr & 7;
                const unsigned short* s =
                    xb + (size_t)(cblk * 64 + ct * 16 + l15) * KD + kt * 32 + lg * 8;
                gll16(s, smem + buf * 32768 + fr * 1024);
            }
        };
        stageB(0, cblk0);                                   // depth-2 prologue
        stageB(1, cblk0 + 1);

        // A frags (mfma_16x16x32 A: row = lane&15, k = kt*32 + (lane>>4)*8 + j)
        short8 afrag[4][8];
        #pragma unroll
        for (int m = 0; m < 4; ++m) {
            const unsigned short* ar = xb + (size_t)(r0 + w * 64 + m * 16 + l15) * KD + lg * 8;
            #pragma unroll
            for (int kt = 0; kt < 8; ++kt)
                afrag[m][kt] = *(const short8*)(ar + kt * 32);
        }
        #pragma unroll
        for (int m = 0; m < 4; ++m)
            #pragma unroll
            for (int kt = 0; kt < 8; ++kt)
                asm volatile("" : "+v"(afrag[m][kt]));      // pin (rolled loop -> AGPRs)

        float rowsum[4][4] = {{0.f}};

        #pragma unroll 1                                    // MUST stay rolled (R4 lesson)
        for (int fi = 0; fi < NI; ++fi) {
            // stage fi+2, then wait for fi's own batch (4 loads/wave/batch):
            // allowed outstanding = batches fi+1, fi+2 (older A-loads may linger: safe)
            if (fi + 2 < NI) {
                stageB((fi + 2) & 3, cblk0 + fi + 2);
                asm volatile("s_waitcnt vmcnt(8)" ::: "memory");
            } else if (fi + 1 < NI) {
                asm volatile("s_waitcnt vmcnt(4)" ::: "memory");
            } else {
                asm volatile("s_waitcnt vmcnt(0)" ::: "memory");
            }
            asm volatile("s_waitcnt lgkmcnt(0)" ::: "memory");  // colred writes visible
            __builtin_amdgcn_s_barrier();                   // ONE barrier per fi
            asm volatile("" ::: "memory");

            // flush previous fi's col-sums (wave 0 only; others go straight to compute)
            if (fi > 0 && tid < 64) {
                const int pc = cblk0 + fi - 1;
                if (pc < rb * 8) {                          // below diag band: mirror path
                    const float* cp = colred + ((fi - 1) & 1) * 512;
                    float cs = 0.f;
                    #pragma unroll
                    for (int w2 = 0; w2 < 8; ++w2) cs += cp[w2 * 64 + tid];
                    rowacc[(size_t)rb * N_ROWS + pc * 64 + tid] = cs;   // slot k=rb
                }
            }

            const char* bbase = smem + (fi & 3) * 32768;
            float* cw = colred + (fi & 1) * 512;
            #pragma unroll
            for (int ct = 0; ct < 4; ++ct) {
                short8 bfrag[8];
                #pragma unroll
                for (int kt = 0; kt < 8; ++kt)              // lane-linear: zero conflicts
                    bfrag[kt] = *(const short8*)(bbase + (ct * 8 + kt) * 1024 + lane * 16);
                f32x4 acc[4];
                #pragma unroll
                for (int m = 0; m < 4; ++m) acc[m] = (f32x4){0.f, 0.f, 0.f, 0.f};
                #pragma unroll
                for (int kt = 0; kt < 8; ++kt)
                    #pragma unroll
                    for (int m = 0; m < 4; ++m)
                        acc[m] = __builtin_amdgcn_mfma_f32_16x16x32_bf16(afrag[m][kt], bfrag[kt], acc[m], 0, 0, 0);
                // C/D: col = lane&15, row-in-16 = (lane>>4)*4 + r
                float csum = 0.f;
                #pragma unroll
                for (int m = 0; m < 4; ++m)
                    #pragma unroll
                    for (int r = 0; r < 4; ++r) {
                        float e = fast_exp2(acc[m][r]);
                        rowsum[m][r] += e;
                        csum += e;
                    }
                csum += __shfl_xor(csum, 16);               // sum wave's 64 rows per col
                csum += __shfl_xor(csum, 32);
                if (lg == 0) cw[w * 64 + ct * 16 + l15] = csum;
            }
            asm volatile("" ::: "memory");
        }

        __syncthreads();                                    // segment end: all compute done

        if (tid < 64) {                                     // flush last fi's col-sums
            const int pc = cblk0 + NI - 1;
            if (pc < rb * 8) {
                const float* cp = colred + ((NI - 1) & 1) * 512;
                float cs = 0.f;
                #pragma unroll
                for (int w2 = 0; w2 < 8; ++w2) cs += cp[w2 * 64 + tid];
                rowacc[(size_t)rb * N_ROWS + pc * 64 + tid] = cs;
            }
        }

        // row-sums: reduce over 16 col-lanes -> rowred -> coalesced store
        #pragma unroll
        for (int m = 0; m < 4; ++m)
            #pragma unroll
            for (int r = 0; r < 4; ++r) {
                float v = rowsum[m][r];
                v += __shfl_xor(v, 1);
                v += __shfl_xor(v, 2);
                v += __shfl_xor(v, 4);
                v += __shfl_xor(v, 8);
                if (l15 == 0) rowred[w * 64 + m * 16 + lg * 4 + r] = v;
            }
        __syncthreads();
        rowacc[(size_t)rowSlot * N_ROWS + r0 + tid] = rowred[tid];

        f = lim;
    }
}

// ---------------- finalize: loss = sum_i log( sum_k rowacc[k][i] ) / 100 ----------------
__global__ void finalize_kernel(const float* __restrict__ rowacc, float* __restrict__ out) {
    int i = blockIdx.x * 256 + threadIdx.x;      // one row per thread, 64 blocks
    float s = 0.f;
    #pragma unroll 8
    for (int k = 0; k < NSLOT; ++k) s += rowacc[(size_t)k * N_ROWS + i];
    float v = logf(s);
    #pragma unroll
    for (int off = 1; off < 64; off <<= 1) v += __shfl_xor(v, off);
    __shared__ float red[4];
    if ((threadIdx.x & 63) == 0) red[threadIdx.x >> 6] = v;
    __syncthreads();
    if (threadIdx.x == 0)
        atomicAdd(out, (red[0] + red[1] + red[2] + red[3]) * 0.01f);
}

extern "C" void kernel_launch(void* const* d_in, const int* in_sizes, int n_in,
                              void* d_out, int out_size, void* d_ws, size_t ws_size,
                              hipStream_t stream) {
    const float* x = (const float*)d_in[0];
    unsigned short* xb = (unsigned short*)d_ws;                           // 8 MB bf16 (pre-scaled)
    float* rowacc = (float*)((char*)d_ws + (size_t)N_ROWS * KD * 2);      // 96 x 16384 f32 (6 MB)
    float* out = (float*)d_out;

    convert_kernel<<<(N_ROWS * KD) / (256 * 4), 256, 0, stream>>>(x, xb, rowacc, out);
    simloss_main<<<NBLK, 512, 0, stream>>>(xb, rowacc);
    finalize_kernel<<<N_ROWS / 256, 256, 0, stream>>>(rowacc, out);
}